// Round 2
// baseline (126662.854 us; speedup 1.0000x reference)
//
#include <hip/hip_runtime.h>
#include <stdint.h>
#include <math.h>

// Problem constants
#define Bv      512
#define INv     64
#define Hv      512
#define OUTv    12
#define Tv      31
#define S0v     8
#define STEPS   (Tv*Bv)        // 15872 sequential LSTM steps per layer

// Workgroup roles — r8 compute structure (bit-exact), XCD-local rings.
// Grid = 256 blocks (1/CU, all co-resident). Dispatch round-robins XCDs
// (xcd = bid%8 on MI355X), so:
//   bid&7==0, sub<16 -> L0 (16 WGs, all on XCD0)
//   bid&7==1         -> L1 (32 WGs, all on XCD1)
//   bid&7==2, sub<16 -> postproc
//   else             -> exit
// Self-loop rings use plain stores (write-through L1->L2) + sc0 loads
// (bypass L1, hit XCD L2). Agent-scope replicas are always written too;
// consumers latch to them if the local ring stalls (wrong mapping => no
// hang, just baseline speed).
#define KA      16             // layer-0 WGs
#define KB      32             // layer-1 WGs
#define KPP     16             // postproc WGs
#define NBLK    256
#define RING    16             // ring depth (power of 2)

// ws layout (bytes), total used 32,772,096 (<= 32,903,168):
//  [0, 128)        : iterflag u32[32]
//  [4096,  +64K)   : h0A u64[RING][512]  — LOCAL ring (plain store / sc0 load), L0 self-loop
//  [69632, +64K)   : h0B u64[RING][512]  — AGENT ring, read by L1 (+ L0 fallback)
//  [135168,+64K)   : y1c u64[RING][512]  — AGENT ring, L0 throttle (+ L1 fallback)
//  [200704,+64K)   : yL  u64[RING][512]  — LOCAL ring, L1 self-loop
//  [266240, ...)   : ys1 float[STEPS][512]  (plain, fenced per iteration)

// ---------------- threefry2x32 (JAX-exact) ----------------
__device__ __forceinline__ uint32_t rotl32(uint32_t v, int r){ return (v<<r)|(v>>(32-r)); }

__device__ __forceinline__ void threefry2x32(uint32_t k0, uint32_t k1,
                                             uint32_t x0, uint32_t x1,
                                             uint32_t& o0, uint32_t& o1) {
  uint32_t ks2 = k0 ^ k1 ^ 0x1BD11BDAu;
  x0 += k0; x1 += k1;
#define TFR(r) { x0 += x1; x1 = rotl32(x1, r); x1 ^= x0; }
  TFR(13) TFR(15) TFR(26) TFR(6)
  x0 += k1;  x1 += ks2 + 1u;
  TFR(17) TFR(29) TFR(16) TFR(24)
  x0 += ks2; x1 += k0 + 2u;
  TFR(13) TFR(15) TFR(26) TFR(6)
  x0 += k0;  x1 += k1 + 3u;
  TFR(17) TFR(29) TFR(16) TFR(24)
  x0 += k1;  x1 += ks2 + 4u;
  TFR(13) TFR(15) TFR(26) TFR(6)
  x0 += ks2; x1 += k0 + 5u;
#undef TFR
  o0 = x0; o1 = x1;
}

__device__ __forceinline__ uint32_t tf_bits32(uint32_t k0, uint32_t k1, uint32_t j) {
  uint32_t a, b;
  threefry2x32(k0, k1, 0u, j, a, b);
  return a ^ b;
}

__device__ __forceinline__ float u32_to_uniform(uint32_t bits) {
  float f = __uint_as_float(0x3F800000u | (bits >> 9)) - 1.0f;
  const float TINY = 1.17549435e-38f;
  return fmaxf(TINY, f + TINY);
}

__device__ __forceinline__ float gumbelf(uint32_t bits) {
  float u = u32_to_uniform(bits);
  return -logf(-logf(u));
}

__device__ __forceinline__ float sigmf(float x) {
  if (x >= 0.f) { float z = expf(-x); return 1.f/(1.f+z); }
  float z = expf(x); return z/(1.f+z);
}

// Butterfly: halve per-lane row-partials across lanes (xor mask m).
template<int N>
__device__ __forceinline__ void bfly_halve(float* v, int m) {
  int lane = threadIdx.x & 63;
  bool up = (lane & m) != 0;
#pragma unroll
  for (int j = 0; j < N/2; ++j) {
    float send = up ? v[j] : v[j + N/2];
    float recv = __shfl_xor(send, m, 64);
    v[j] = (up ? v[j + N/2] : v[j]) + recv;
  }
}

__device__ __forceinline__ uint64_t aload64(const uint64_t* p){
  return __hip_atomic_load(p, __ATOMIC_RELAXED, __HIP_MEMORY_SCOPE_AGENT);
}
__device__ __forceinline__ void astore64(uint64_t* p, uint64_t v){
  __hip_atomic_store(p, v, __ATOMIC_RELAXED, __HIP_MEMORY_SCOPE_AGENT);
}
__device__ __forceinline__ uint32_t aload32(const uint32_t* p){
  return __hip_atomic_load(p, __ATOMIC_RELAXED, __HIP_MEMORY_SCOPE_AGENT);
}
__device__ __forceinline__ void astore32(uint32_t* p, uint32_t v){
  __hip_atomic_store(p, v, __ATOMIC_RELAXED, __HIP_MEMORY_SCOPE_AGENT);
}
// LOCAL-ring ops: plain store (write-through L1 -> home L2); sc0 load
// (bypass own CU L1, served by XCD L2). Only correct producer<->consumer
// on the SAME XCD — consumers latch to the agent replica if stalled.
__device__ __forceinline__ void store_plain64(uint64_t* p, uint64_t v){
  asm volatile("global_store_dwordx2 %0, %1, off" :: "v"(p), "v"(v) : "memory");
}
__device__ __forceinline__ uint64_t load_sc0(const uint64_t* p){
  uint64_t r;
  asm volatile("global_load_dwordx2 %0, %1, off sc0\n\ts_waitcnt vmcnt(0)"
               : "=&v"(r) : "v"(p) : "memory");
  return r;
}
__device__ __forceinline__ uint32_t tagof(uint64_t w){ return (uint32_t)(w>>32); }
__device__ __forceinline__ float    valof(uint64_t w){ return __uint_as_float((uint32_t)w); }
__device__ __forceinline__ uint64_t mkword(uint32_t t, float v){
  return ((uint64_t)t<<32) | (uint64_t)__float_as_uint(v);
}

__global__ __launch_bounds__(512, 1)
void net_persistent(const float* __restrict__ Wih0, const float* __restrict__ Whh0,
                    const float* __restrict__ b0,
                    const float* __restrict__ Wih1, const float* __restrict__ Whh1,
                    const float* __restrict__ b1,
                    const float* __restrict__ gamma, const float* __restrict__ beta,
                    const float* __restrict__ Wout, const float* __restrict__ bout,
                    const float* __restrict__ h0in, const float* __restrict__ c0in,
                    float* __restrict__ out, uint32_t* __restrict__ wsu)
{
  uint32_t* iterflag = wsu;                              // [32]
  uint64_t* h0A = (uint64_t*)((char*)wsu + 4096);                        // local
  uint64_t* h0B = (uint64_t*)((char*)wsu + 4096 + (size_t)RING*Hv*8);    // agent
  uint64_t* y1c = (uint64_t*)((char*)wsu + 4096 + (size_t)2*RING*Hv*8);  // agent
  uint64_t* yL  = (uint64_t*)((char*)wsu + 4096 + (size_t)3*RING*Hv*8);  // local
  float*    ys1 = (float*)((char*)wsu + 4096 + (size_t)4*RING*Hv*8);

  const int bid  = blockIdx.x;
  const int tid  = threadIdx.x;
  const int wave = tid >> 6;
  const int lane = tid & 63;
  const int role = bid & 7;
  const int sub  = bid >> 3;

  __shared__ float hbuf[2][Hv];      // L0 input double-buffer
  __shared__ float xbuf[2][2*Hv];    // L1 input double-buffer [x | hprev]
  __shared__ float Wout_s[OUTv*Hv];
  __shared__ float mu_s[Hv], isd_s[Hv], gam_s[Hv], bet_s[Hv];

  if (role == 0 && sub < KA) {
    // ================= Layer 0 (autonomous: x = ones folded) =================
    // 16 WGs x 512 threads; wave (0..7) owns 4 h-indices. (identical compute to r8)
    const int hbase = sub*32;
    float w[128];
#pragma unroll
    for (int jl = 0; jl < 4; ++jl)
#pragma unroll
      for (int g = 0; g < 4; ++g) {
        int r = jl*4 + g;
        const float* rp = Whh0 + (size_t)(g*Hv + hbase + wave*4 + jl)*Hv;
#pragma unroll
        for (int k = 0; k < 2; ++k) {
          float4 q = *(const float4*)(rp + k*256 + lane*4);
          w[r*8+k*4+0]=q.x; w[r*8+k*4+1]=q.y; w[r*8+k*4+2]=q.z; w[r*8+k*4+3]=q.w;
        }
      }
    // per-lane gate constants (x = ones folded) + c-state for h-index lane&3
    const int jsel = lane & 3;
    const int hg = hbase + wave*4 + jsel;
    float cgi, cgf, cgg, cgo;
    {
      float s0=b0[0*Hv+hg], s1=b0[1*Hv+hg], s2=b0[2*Hv+hg], s3=b0[3*Hv+hg];
      for (int k = 0; k < INv; ++k) {
        s0 += Wih0[(size_t)(0*Hv+hg)*INv+k];
        s1 += Wih0[(size_t)(1*Hv+hg)*INv+k];
        s2 += Wih0[(size_t)(2*Hv+hg)*INv+k];
        s3 += Wih0[(size_t)(3*Hv+hg)*INv+k];
      }
      cgi=s0; cgf=s1; cgg=s2; cgo=s3;
    }
    float cst = c0in[hg];
    bool fbL = false;          // latched: local ring failed -> use agent replica
    int  fbAcc = 0;            // cumulative excess poll iterations

    for (int s = 0; s < STEPS; ++s) {
      const int par = s & 1;
      // ring throttle every 8 steps: require L1 done step >= s-9 (tag >= s-8)
      // before overwriting h0B slot (ring depth 16 => L0 <= L1done + 16).
      if ((s & 7) == 0 && s >= 16) {
        const uint64_t* tp = y1c + (size_t)((s-9)&(RING-1))*Hv + lane*8;
        uint32_t need = (uint32_t)(s - 8);
        for (;;) {
          uint32_t t = tagof(aload64(tp));
          if (__all((int)(t >= need && t <= (uint32_t)STEPS))) break;
          __builtin_amdgcn_s_sleep(1);
        }
      }
      // phase A: poll previous h into LDS — 1 word per thread (LOCAL ring)
      {
        int idx = tid;
        if (s == 0) {
          hbuf[0][idx] = h0in[idx];
        } else {
          const int slot = (s-1)&(RING-1);
          uint64_t* lp = h0A + (size_t)slot*Hv + idx;
          const uint64_t* ap = h0B + (size_t)slot*Hv + idx;
          uint32_t want = (uint32_t)s;
          uint64_t a = 0; bool got = false;
          if (!fbL) {
            int it = 0;
            for (;;) {
              a = load_sc0(lp);
              if (tagof(a) == want) { got = true; break; }
              if (++it > 4) { if (++fbAcc > 8192) { fbL = true; break; } }
            }
          }
          if (!got) {
            a = aload64(ap);
            while (tagof(a) != want) a = aload64(ap);
          }
          hbuf[par][idx] = valof(a);
        }
      }
      __syncthreads();
      // compute: 16 rows x 8 cols per lane
      const float4* hv = (const float4*)(hbuf[par]);
      float4 vA = hv[lane], vB = hv[64 + lane];
      float acc[16];
#pragma unroll
      for (int r = 0; r < 16; ++r) {
        float a = 0.f;
        a = fmaf(w[r*8+0], vA.x, a); a = fmaf(w[r*8+1], vA.y, a);
        a = fmaf(w[r*8+2], vA.z, a); a = fmaf(w[r*8+3], vA.w, a);
        a = fmaf(w[r*8+4], vB.x, a); a = fmaf(w[r*8+5], vB.y, a);
        a = fmaf(w[r*8+6], vB.z, a); a = fmaf(w[r*8+7], vB.w, a);
        acc[r] = a;
      }
      bfly_halve<16>(acc, 32);
      bfly_halve<8>(acc, 16);
      bfly_halve<4>(acc, 8);
      bfly_halve<2>(acc, 4);
      acc[0] += __shfl_xor(acc[0], 2, 64);
      acc[0] += __shfl_xor(acc[0], 1, 64);   // lane holds row (lane>>2)
      // every lane gathers the 4 gates of h-index jsel
      float gi = __shfl(acc[0], 16*jsel + 0,  64);
      float gf = __shfl(acc[0], 16*jsel + 4,  64);
      float gg = __shfl(acc[0], 16*jsel + 8,  64);
      float go = __shfl(acc[0], 16*jsel + 12, 64);
      float cc = sigmf(gf+cgf)*cst + sigmf(gi+cgi)*tanhf(gg+cgg);
      float hh = sigmf(go+cgo)*tanhf(cc);
      cst = cc;
      if (lane < 8) {   // lanes 0-3 -> local ring (L0 self-loop); 4-7 -> agent (L1 + fallback)
        uint64_t w64 = mkword((uint32_t)(s+1), hh);
        size_t off = (size_t)(s&(RING-1))*Hv + hg;
        if (lane < 4) store_plain64(h0A + off, w64);
        else          astore64(h0B + off, w64);
      }
    }
  } else if (role == 1) {
    // ================= Layer 1 =================
    // 32 WGs x 512 threads; wave (0..7) owns 2 h-indices. (identical compute to r8)
    const int wg1 = sub;
    const int hbase = wg1*16;
    float w[128];
#pragma unroll
    for (int jl = 0; jl < 2; ++jl)
#pragma unroll
      for (int g = 0; g < 4; ++g) {
        int r = jl*4 + g;
        int row = g*Hv + hbase + wave*2 + jl;
#pragma unroll
        for (int k = 0; k < 4; ++k) {
          int col = k*256 + lane*4;
          const float* M = (col < Hv) ? (Wih1 + (size_t)row*Hv + col)
                                      : (Whh1 + (size_t)row*Hv + (col - Hv));
          float4 q = *(const float4*)M;
          w[r*16+k*4+0]=q.x; w[r*16+k*4+1]=q.y; w[r*16+k*4+2]=q.z; w[r*16+k*4+3]=q.w;
        }
      }
    const int jsel = lane & 1;
    const int hg = hbase + wave*2 + jsel;
    float cgi = b1[0*Hv+hg], cgf = b1[1*Hv+hg],
          cgg = b1[2*Hv+hg], cgo = b1[3*Hv+hg];
    float cst = c0in[Hv + hg];
    bool fbL = false;
    int  fbAcc = 0;

    for (int s = 0; s < STEPS; ++s) {
      const int par = s & 1;
      // phase A: poll x = h0[s] (tag s+1, agent h0B — feed-forward, pipelined)
      //          and hprev = y1[s-1] (tag s, LOCAL yL ring)
      {
        int j0 = tid*2;
        if (j0 < Hv) {
          const uint64_t* src = h0B + (size_t)(s&(RING-1))*Hv + j0;
          uint32_t want = (uint32_t)(s+1);
          uint64_t a = aload64(src), b2 = aload64(src+1);
          while (tagof(a) != want || tagof(b2) != want) {
            a = aload64(src); b2 = aload64(src+1);
          }
          xbuf[par][j0] = valof(a); xbuf[par][j0+1] = valof(b2);
        } else {
          if (s == 0) {
            xbuf[0][j0]   = h0in[j0];     // h0in[512..1023] = layer-1 h0
            xbuf[0][j0+1] = h0in[j0+1];
          } else {
            const int slot = (s-1)&(RING-1);
            uint64_t* lp = yL + (size_t)slot*Hv + (j0 - Hv);
            const uint64_t* ap = y1c + (size_t)slot*Hv + (j0 - Hv);
            uint32_t want = (uint32_t)s;
            uint64_t a = 0, b2 = 0; bool got = false;
            if (!fbL) {
              int it = 0;
              for (;;) {
                a = load_sc0(lp); b2 = load_sc0(lp+1);
                if (tagof(a) == want && tagof(b2) == want) { got = true; break; }
                if (++it > 4) { if (++fbAcc > 8192) { fbL = true; break; } }
              }
            }
            if (!got) {
              a = aload64(ap); b2 = aload64(ap+1);
              while (tagof(a) != want || tagof(b2) != want) {
                a = aload64(ap); b2 = aload64(ap+1);
              }
            }
            xbuf[par][j0] = valof(a); xbuf[par][j0+1] = valof(b2);
          }
        }
      }
      __syncthreads();
      // compute: 8 rows x 16 cols per lane
      const float4* xv = (const float4*)(xbuf[par]);
      float4 v0 = xv[lane], v1 = xv[64+lane], v2 = xv[128+lane], v3 = xv[192+lane];
      float acc[8];
#pragma unroll
      for (int r = 0; r < 8; ++r) {
        float a = 0.f;
        a = fmaf(w[r*16+ 0], v0.x, a); a = fmaf(w[r*16+ 1], v0.y, a);
        a = fmaf(w[r*16+ 2], v0.z, a); a = fmaf(w[r*16+ 3], v0.w, a);
        a = fmaf(w[r*16+ 4], v1.x, a); a = fmaf(w[r*16+ 5], v1.y, a);
        a = fmaf(w[r*16+ 6], v1.z, a); a = fmaf(w[r*16+ 7], v1.w, a);
        a = fmaf(w[r*16+ 8], v2.x, a); a = fmaf(w[r*16+ 9], v2.y, a);
        a = fmaf(w[r*16+10], v2.z, a); a = fmaf(w[r*16+11], v2.w, a);
        a = fmaf(w[r*16+12], v3.x, a); a = fmaf(w[r*16+13], v3.y, a);
        a = fmaf(w[r*16+14], v3.z, a); a = fmaf(w[r*16+15], v3.w, a);
        acc[r] = a;
      }
      bfly_halve<8>(acc, 32);
      bfly_halve<4>(acc, 16);
      bfly_halve<2>(acc, 8);
      acc[0] += __shfl_xor(acc[0], 4, 64);
      acc[0] += __shfl_xor(acc[0], 2, 64);
      acc[0] += __shfl_xor(acc[0], 1, 64);   // lane holds row (lane>>3)
      float gi = __shfl(acc[0], 32*jsel + 0,  64);
      float gf = __shfl(acc[0], 32*jsel + 8,  64);
      float gg = __shfl(acc[0], 32*jsel + 16, 64);
      float go = __shfl(acc[0], 32*jsel + 24, 64);
      float cc = sigmf(gf+cgf)*cst + sigmf(gi+cgi)*tanhf(gg+cgg);
      float hh = sigmf(go+cgo)*tanhf(cc);
      cst = cc;
      {
        uint64_t w64 = mkword((uint32_t)(s+1), hh);
        size_t off = (size_t)(s&(RING-1))*Hv + hg;
        if (lane < 2)      store_plain64(yL + off, w64);      // local self-loop
        else if (lane < 4) astore64(y1c + off, w64);          // agent (throttle + fallback)
        else if (lane < 6) ys1[(size_t)s*Hv + hg] = hh;       // plain store for postproc
      }
      if ((s & 511) == 511) {
        __syncthreads();   // drain all waves' ys1 stores
        if (tid == 0) {
          __builtin_amdgcn_fence(__ATOMIC_RELEASE, "agent");
          astore32(iterflag + wg1, (uint32_t)((s >> 9) + 1));
        }
      }
    }
  } else if (role == 2 && sub < KPP) {
    // ================= Postprocess (512 threads) =================
    const int p = sub;
    for (int r = tid; r < OUTv*Hv; r += 512) Wout_s[r] = Wout[r];
    for (int h = tid; h < Hv; h += 512) { gam_s[h] = gamma[h]; bet_s[h] = beta[h]; }
    float bo[OUTv];
#pragma unroll
    for (int o = 0; o < OUTv; ++o) bo[o] = bout[o];
    __syncthreads();

    for (int i = p; i < Tv; i += KPP) {
      const uint32_t tgt = (uint32_t)(i + 1);
      if (tid < 64) {
        for (;;) {
          uint32_t v = aload32(iterflag + (lane & 31));
          if (__all((int)(v >= tgt && v <= (uint32_t)Tv))) break;
          __builtin_amdgcn_s_sleep(16);
        }
      }
      __syncthreads();
      __builtin_amdgcn_fence(__ATOMIC_ACQUIRE, "agent");

      const float* Y = ys1 + (size_t)i * Bv * Hv;

      for (int h = tid; h < Hv; h += 512) {
        double sum = 0.0, sq = 0.0;
        for (int b = 0; b < Bv; ++b) {
          double v = (double)Y[(size_t)b*Hv + h];
          sum += v; sq += v*v;
        }
        double mu = sum * (1.0/512.0);
        double var = sq * (1.0/512.0) - mu*mu;
        if (var < 0.0) var = 0.0;
        mu_s[h]  = (float)mu;
        isd_s[h] = (float)(1.0 / sqrt(var + 1e-5));
      }
      __syncthreads();

      uint32_t k0, k1;
      threefry2x32(0u, 42u, 0u, (uint32_t)i, k0, k1);

      for (int b = tid; b < Bv; b += 512) {
        float lg[OUTv];
#pragma unroll
        for (int o = 0; o < OUTv; ++o) lg[o] = 0.f;
        const float* Yb = Y + (size_t)b * Hv;
        for (int h = 0; h < Hv; ++h) {
          float yn = (Yb[h] - mu_s[h]) * isd_s[h] * gam_s[h] + bet_s[h];
          float gv = expf(-yn*yn);
#pragma unroll
          for (int o = 0; o < OUTv; ++o) lg[o] = fmaf(gv, Wout_s[o*Hv + h], lg[o]);
        }
#pragma unroll
        for (int o = 0; o < OUTv; ++o) lg[o] += bo[o];

        int action; float la;
        if (i < 15) {
          float best = -3.0e38f; int bi = 0; float bl = lg[0];
#pragma unroll
          for (int o = 0; o < OUTv; ++o) {
            uint32_t bits = tf_bits32(k0, k1, (uint32_t)(b*12 + o));
            float z = gumbelf(bits) + lg[o];
            if (z > best) { best = z; bi = o; bl = lg[o]; }
          }
          action = bi; la = bl;
        } else {
          float best = -3.0e38f; int bi = 0; float bl = lg[S0v];
#pragma unroll
          for (int o = 0; o < 4; ++o) {
            uint32_t bits = tf_bits32(k0, k1, (uint32_t)(b*4 + o));
            float z = gumbelf(bits) + lg[S0v + o];
            if (z > best) { best = z; bi = o; bl = lg[S0v + o]; }
          }
          action = S0v + bi; la = bl;
        }

        float mx = lg[0];
#pragma unroll
        for (int o = 1; o < OUTv; ++o) mx = fmaxf(mx, lg[o]);
        float se = 0.f;
#pragma unroll
        for (int o = 0; o < OUTv; ++o) se += expf(lg[o] - mx);
        float lp = (la - mx) - logf(se);

        out[i*Bv + b]         = (float)action;
        out[STEPS + i*Bv + b] = lp;
      }
    }
  }
}

extern "C" void kernel_launch(void* const* d_in, const int* in_sizes, int n_in,
                              void* d_out, int out_size, void* d_ws, size_t ws_size,
                              hipStream_t stream) {
  const float* Wih0 = (const float*)d_in[0];
  const float* Whh0 = (const float*)d_in[1];
  const float* b0   = (const float*)d_in[2];
  const float* Wih1 = (const float*)d_in[3];
  const float* Whh1 = (const float*)d_in[4];
  const float* b1   = (const float*)d_in[5];
  const float* gam  = (const float*)d_in[6];
  const float* bet  = (const float*)d_in[7];
  const float* Wout = (const float*)d_in[8];
  const float* bout = (const float*)d_in[9];
  const float* h0   = (const float*)d_in[10];
  const float* c0   = (const float*)d_in[11];

  net_persistent<<<dim3(NBLK), dim3(512), 0, stream>>>(
      Wih0, Whh0, b0, Wih1, Whh1, b1, gam, bet, Wout, bout, h0, c0,
      (float*)d_out, (uint32_t*)d_ws);
}

// Round 3
// 110140.869 us; speedup vs baseline: 1.1500x; 1.1500x over previous
//
#include <hip/hip_runtime.h>
#include <stdint.h>
#include <math.h>

// Problem constants
#define Bv      512
#define INv     64
#define Hv      512
#define OUTv    12
#define Tv      31
#define S0v     8
#define STEPS   (Tv*Bv)        // 15872 sequential LSTM steps per layer

// Workgroup roles — r8 config (champion structure): 512-thread blocks.
// R3: per-lane direct-to-register polls (no LDS staging, no per-step
// __syncthreads) + atomic-swap publish (executes at coherence point).
#define KA      16             // layer-0 WGs (32 h each, 4 h per wave)
#define KB      32             // layer-1 WGs (16 h each, 2 h per wave)
#define KPP     16             // postproc WGs
#define NBLK    (KA+KB+KPP)    // 64 blocks -> co-resident
#define RING    32             // comm ring depth (power of 2)

// ws layout (bytes), total 32,903,168:
//  [0, 128)       : iterflag u32[32]
//  [4096,   +128K): h0A u64[RING][512]  — read by L0
//  [135168, +128K): h0B u64[RING][512]  — read by L1
//  [266240, +128K): y1c u64[RING][512]  — read by L1 (+ L0 throttle, sparse)
//  [397312, ...)  : ys1 float[STEPS][512]  (plain, fenced per iteration)

// ---------------- threefry2x32 (JAX-exact) ----------------
__device__ __forceinline__ uint32_t rotl32(uint32_t v, int r){ return (v<<r)|(v>>(32-r)); }

__device__ __forceinline__ void threefry2x32(uint32_t k0, uint32_t k1,
                                             uint32_t x0, uint32_t x1,
                                             uint32_t& o0, uint32_t& o1) {
  uint32_t ks2 = k0 ^ k1 ^ 0x1BD11BDAu;
  x0 += k0; x1 += k1;
#define TFR(r) { x0 += x1; x1 = rotl32(x1, r); x1 ^= x0; }
  TFR(13) TFR(15) TFR(26) TFR(6)
  x0 += k1;  x1 += ks2 + 1u;
  TFR(17) TFR(29) TFR(16) TFR(24)
  x0 += ks2; x1 += k0 + 2u;
  TFR(13) TFR(15) TFR(26) TFR(6)
  x0 += k0;  x1 += k1 + 3u;
  TFR(17) TFR(29) TFR(16) TFR(24)
  x0 += k1;  x1 += ks2 + 4u;
  TFR(13) TFR(15) TFR(26) TFR(6)
  x0 += ks2; x1 += k0 + 5u;
#undef TFR
  o0 = x0; o1 = x1;
}

__device__ __forceinline__ uint32_t tf_bits32(uint32_t k0, uint32_t k1, uint32_t j) {
  uint32_t a, b;
  threefry2x32(k0, k1, 0u, j, a, b);
  return a ^ b;
}

__device__ __forceinline__ float u32_to_uniform(uint32_t bits) {
  float f = __uint_as_float(0x3F800000u | (bits >> 9)) - 1.0f;
  const float TINY = 1.17549435e-38f;
  return fmaxf(TINY, f + TINY);
}

__device__ __forceinline__ float gumbelf(uint32_t bits) {
  float u = u32_to_uniform(bits);
  return -logf(-logf(u));
}

__device__ __forceinline__ float sigmf(float x) {
  if (x >= 0.f) { float z = expf(-x); return 1.f/(1.f+z); }
  float z = expf(x); return z/(1.f+z);
}

// Butterfly: halve per-lane row-partials across lanes (xor mask m).
template<int N>
__device__ __forceinline__ void bfly_halve(float* v, int m) {
  int lane = threadIdx.x & 63;
  bool up = (lane & m) != 0;
#pragma unroll
  for (int j = 0; j < N/2; ++j) {
    float send = up ? v[j] : v[j + N/2];
    float recv = __shfl_xor(send, m, 64);
    v[j] = (up ? v[j + N/2] : v[j]) + recv;
  }
}

__device__ __forceinline__ uint64_t aload64(const uint64_t* p){
  return __hip_atomic_load(p, __ATOMIC_RELAXED, __HIP_MEMORY_SCOPE_AGENT);
}
__device__ __forceinline__ void aswap64(uint64_t* p, uint64_t v){
  (void)__hip_atomic_exchange(p, v, __ATOMIC_RELAXED, __HIP_MEMORY_SCOPE_AGENT);
}
__device__ __forceinline__ uint32_t aload32(const uint32_t* p){
  return __hip_atomic_load(p, __ATOMIC_RELAXED, __HIP_MEMORY_SCOPE_AGENT);
}
__device__ __forceinline__ void astore32(uint32_t* p, uint32_t v){
  __hip_atomic_store(p, v, __ATOMIC_RELAXED, __HIP_MEMORY_SCOPE_AGENT);
}
__device__ __forceinline__ uint32_t tagof(uint64_t w){ return (uint32_t)(w>>32); }
__device__ __forceinline__ float    valof(uint64_t w){ return __uint_as_float((uint32_t)w); }
__device__ __forceinline__ uint64_t mkword(uint32_t t, float v){
  return ((uint64_t)t<<32) | (uint64_t)__float_as_uint(v);
}

__global__ __launch_bounds__(512, 1)
void net_persistent(const float* __restrict__ Wih0, const float* __restrict__ Whh0,
                    const float* __restrict__ b0,
                    const float* __restrict__ Wih1, const float* __restrict__ Whh1,
                    const float* __restrict__ b1,
                    const float* __restrict__ gamma, const float* __restrict__ beta,
                    const float* __restrict__ Wout, const float* __restrict__ bout,
                    const float* __restrict__ h0in, const float* __restrict__ c0in,
                    float* __restrict__ out, uint32_t* __restrict__ wsu)
{
  uint32_t* iterflag = wsu;                              // [32]
  uint64_t* h0A = (uint64_t*)((char*)wsu + 4096);
  uint64_t* h0B = (uint64_t*)((char*)wsu + 4096 + (size_t)RING*Hv*8);
  uint64_t* y1c = (uint64_t*)((char*)wsu + 4096 + (size_t)2*RING*Hv*8);
  float*    ys1 = (float*)((char*)wsu + 4096 + (size_t)3*RING*Hv*8);

  const int bid  = blockIdx.x;
  const int tid  = threadIdx.x;
  const int wave = tid >> 6;
  const int lane = tid & 63;

  __shared__ float Wout_s[OUTv*Hv];
  __shared__ float mu_s[Hv], isd_s[Hv], gam_s[Hv], bet_s[Hv];

  if (bid < KA) {
    // ================= Layer 0 (autonomous: x = ones folded) =================
    // 16 WGs x 512 threads; wave (0..7) owns 4 h-indices.
    const int hbase = bid*32;
    float w[128];
#pragma unroll
    for (int jl = 0; jl < 4; ++jl)
#pragma unroll
      for (int g = 0; g < 4; ++g) {
        int r = jl*4 + g;
        const float* rp = Whh0 + (size_t)(g*Hv + hbase + wave*4 + jl)*Hv;
#pragma unroll
        for (int k = 0; k < 2; ++k) {
          float4 q = *(const float4*)(rp + k*256 + lane*4);
          w[r*8+k*4+0]=q.x; w[r*8+k*4+1]=q.y; w[r*8+k*4+2]=q.z; w[r*8+k*4+3]=q.w;
        }
      }
    // per-lane gate constants (x = ones folded) + c-state for h-index lane&3
    const int jsel = lane & 3;
    const int hg = hbase + wave*4 + jsel;
    float cgi, cgf, cgg, cgo;
    {
      float s0=b0[0*Hv+hg], s1=b0[1*Hv+hg], s2=b0[2*Hv+hg], s3=b0[3*Hv+hg];
      for (int k = 0; k < INv; ++k) {
        s0 += Wih0[(size_t)(0*Hv+hg)*INv+k];
        s1 += Wih0[(size_t)(1*Hv+hg)*INv+k];
        s2 += Wih0[(size_t)(2*Hv+hg)*INv+k];
        s3 += Wih0[(size_t)(3*Hv+hg)*INv+k];
      }
      cgi=s0; cgf=s1; cgg=s2; cgo=s3;
    }
    float cst = c0in[hg];
    const int c0 = 4*lane, c1 = 256 + 4*lane;   // the 8 h-indices this lane consumes

    for (int s = 0; s < STEPS; ++s) {
      // ring throttle every 16 steps (per-wave; unchanged from champion)
      if ((s & 15) == 0 && s >= 32) {
        const uint64_t* tp = y1c + (size_t)((s-17)&(RING-1))*Hv + lane*8;
        uint32_t need = (uint32_t)(s - 16);
        for (;;) {
          uint32_t t = tagof(aload64(tp));
          if (__all((int)(t >= need && t <= (uint32_t)STEPS))) break;
          __builtin_amdgcn_s_sleep(1);
        }
      }
      // phase A: per-lane direct poll of the 8 words this lane consumes
      float4 vA, vB;
      if (s == 0) {
        vA = *(const float4*)(h0in + c0);
        vB = *(const float4*)(h0in + c1);
      } else {
        const uint64_t* base = h0A + (size_t)((s-1)&(RING-1))*Hv;
        const uint32_t want = (uint32_t)s;
        uint64_t a0,a1,a2,a3,b0w,b1w,b2w,b3w;
        for (;;) {
          a0 = aload64(base+c0+0); a1 = aload64(base+c0+1);
          a2 = aload64(base+c0+2); a3 = aload64(base+c0+3);
          b0w= aload64(base+c1+0); b1w= aload64(base+c1+1);
          b2w= aload64(base+c1+2); b3w= aload64(base+c1+3);
          if (tagof(a0)==want && tagof(a1)==want && tagof(a2)==want && tagof(a3)==want &&
              tagof(b0w)==want && tagof(b1w)==want && tagof(b2w)==want && tagof(b3w)==want)
            break;
        }
        vA.x=valof(a0); vA.y=valof(a1); vA.z=valof(a2); vA.w=valof(a3);
        vB.x=valof(b0w); vB.y=valof(b1w); vB.z=valof(b2w); vB.w=valof(b3w);
      }
      // compute: 16 rows x 8 cols per lane (identical FMA order to champion)
      float acc[16];
#pragma unroll
      for (int r = 0; r < 16; ++r) {
        float a = 0.f;
        a = fmaf(w[r*8+0], vA.x, a); a = fmaf(w[r*8+1], vA.y, a);
        a = fmaf(w[r*8+2], vA.z, a); a = fmaf(w[r*8+3], vA.w, a);
        a = fmaf(w[r*8+4], vB.x, a); a = fmaf(w[r*8+5], vB.y, a);
        a = fmaf(w[r*8+6], vB.z, a); a = fmaf(w[r*8+7], vB.w, a);
        acc[r] = a;
      }
      bfly_halve<16>(acc, 32);
      bfly_halve<8>(acc, 16);
      bfly_halve<4>(acc, 8);
      bfly_halve<2>(acc, 4);
      acc[0] += __shfl_xor(acc[0], 2, 64);
      acc[0] += __shfl_xor(acc[0], 1, 64);   // lane holds row (lane>>2)
      // every lane gathers the 4 gates of h-index jsel
      float gi = __shfl(acc[0], 16*jsel + 0,  64);
      float gf = __shfl(acc[0], 16*jsel + 4,  64);
      float gg = __shfl(acc[0], 16*jsel + 8,  64);
      float go = __shfl(acc[0], 16*jsel + 12, 64);
      float cc = sigmf(gf+cgf)*cst + sigmf(gi+cgi)*tanhf(gg+cgg);
      float hh = sigmf(go+cgo)*tanhf(cc);
      cst = cc;
      if (lane < 8) {   // lanes 0-3 -> replica A (L0 readers); 4-7 -> B (L1 readers)
        uint64_t* dst = (lane < 4) ? h0A : h0B;
        aswap64(dst + (size_t)(s&(RING-1))*Hv + hg, mkword((uint32_t)(s+1), hh));
      }
    }
  } else if (bid < KA + KB) {
    // ================= Layer 1 =================
    // 32 WGs x 512 threads; wave (0..7) owns 2 h-indices.
    const int wg1 = bid - KA;
    const int hbase = wg1*16;
    float w[128];
#pragma unroll
    for (int jl = 0; jl < 2; ++jl)
#pragma unroll
      for (int g = 0; g < 4; ++g) {
        int r = jl*4 + g;
        int row = g*Hv + hbase + wave*2 + jl;
#pragma unroll
        for (int k = 0; k < 4; ++k) {
          int col = k*256 + lane*4;
          const float* M = (col < Hv) ? (Wih1 + (size_t)row*Hv + col)
                                      : (Whh1 + (size_t)row*Hv + (col - Hv));
          float4 q = *(const float4*)M;
          w[r*16+k*4+0]=q.x; w[r*16+k*4+1]=q.y; w[r*16+k*4+2]=q.z; w[r*16+k*4+3]=q.w;
        }
      }
    const int jsel = lane & 1;
    const int hg = hbase + wave*2 + jsel;
    float cgi = b1[0*Hv+hg], cgf = b1[1*Hv+hg],
          cgg = b1[2*Hv+hg], cgo = b1[3*Hv+hg];
    float cst = c0in[Hv + hg];
    const int c0 = 4*lane, c1 = 256 + 4*lane;

    for (int s = 0; s < STEPS; ++s) {
      // phase A: per-lane poll — x = h0[s] (tag s+1) and hprev = y1[s-1] (tag s)
      float4 v0, v1, v2, v3;
      {
        const uint64_t* bx = h0B + (size_t)(s&(RING-1))*Hv;
        const uint32_t wantx = (uint32_t)(s+1);
        if (s == 0) {
          // hprev from h0in (layer-1 slice); x still polled from L0's step-0 publish
          v2 = *(const float4*)(h0in + 512 + c0);
          v3 = *(const float4*)(h0in + 512 + c1);
          uint64_t x0,x1,x2,x3,x4,x5,x6,x7;
          for (;;) {
            x0=aload64(bx+c0+0); x1=aload64(bx+c0+1); x2=aload64(bx+c0+2); x3=aload64(bx+c0+3);
            x4=aload64(bx+c1+0); x5=aload64(bx+c1+1); x6=aload64(bx+c1+2); x7=aload64(bx+c1+3);
            if (tagof(x0)==wantx && tagof(x1)==wantx && tagof(x2)==wantx && tagof(x3)==wantx &&
                tagof(x4)==wantx && tagof(x5)==wantx && tagof(x6)==wantx && tagof(x7)==wantx)
              break;
          }
          v0.x=valof(x0); v0.y=valof(x1); v0.z=valof(x2); v0.w=valof(x3);
          v1.x=valof(x4); v1.y=valof(x5); v1.z=valof(x6); v1.w=valof(x7);
        } else {
          const uint64_t* by = y1c + (size_t)((s-1)&(RING-1))*Hv;
          const uint32_t wanty = (uint32_t)s;
          uint64_t x0,x1,x2,x3,x4,x5,x6,x7, y0,y1,y2,y3,y4,y5,y6,y7;
          for (;;) {
            x0=aload64(bx+c0+0); x1=aload64(bx+c0+1); x2=aload64(bx+c0+2); x3=aload64(bx+c0+3);
            x4=aload64(bx+c1+0); x5=aload64(bx+c1+1); x6=aload64(bx+c1+2); x7=aload64(bx+c1+3);
            y0=aload64(by+c0+0); y1=aload64(by+c0+1); y2=aload64(by+c0+2); y3=aload64(by+c0+3);
            y4=aload64(by+c1+0); y5=aload64(by+c1+1); y6=aload64(by+c1+2); y7=aload64(by+c1+3);
            if (tagof(x0)==wantx && tagof(x1)==wantx && tagof(x2)==wantx && tagof(x3)==wantx &&
                tagof(x4)==wantx && tagof(x5)==wantx && tagof(x6)==wantx && tagof(x7)==wantx &&
                tagof(y0)==wanty && tagof(y1)==wanty && tagof(y2)==wanty && tagof(y3)==wanty &&
                tagof(y4)==wanty && tagof(y5)==wanty && tagof(y6)==wanty && tagof(y7)==wanty)
              break;
          }
          v0.x=valof(x0); v0.y=valof(x1); v0.z=valof(x2); v0.w=valof(x3);
          v1.x=valof(x4); v1.y=valof(x5); v1.z=valof(x6); v1.w=valof(x7);
          v2.x=valof(y0); v2.y=valof(y1); v2.z=valof(y2); v2.w=valof(y3);
          v3.x=valof(y4); v3.y=valof(y5); v3.z=valof(y6); v3.w=valof(y7);
        }
      }
      // compute: 8 rows x 16 cols per lane (identical FMA order to champion)
      float acc[8];
#pragma unroll
      for (int r = 0; r < 8; ++r) {
        float a = 0.f;
        a = fmaf(w[r*16+ 0], v0.x, a); a = fmaf(w[r*16+ 1], v0.y, a);
        a = fmaf(w[r*16+ 2], v0.z, a); a = fmaf(w[r*16+ 3], v0.w, a);
        a = fmaf(w[r*16+ 4], v1.x, a); a = fmaf(w[r*16+ 5], v1.y, a);
        a = fmaf(w[r*16+ 6], v1.z, a); a = fmaf(w[r*16+ 7], v1.w, a);
        a = fmaf(w[r*16+ 8], v2.x, a); a = fmaf(w[r*16+ 9], v2.y, a);
        a = fmaf(w[r*16+10], v2.z, a); a = fmaf(w[r*16+11], v2.w, a);
        a = fmaf(w[r*16+12], v3.x, a); a = fmaf(w[r*16+13], v3.y, a);
        a = fmaf(w[r*16+14], v3.z, a); a = fmaf(w[r*16+15], v3.w, a);
        acc[r] = a;
      }
      bfly_halve<8>(acc, 32);
      bfly_halve<4>(acc, 16);
      bfly_halve<2>(acc, 8);
      acc[0] += __shfl_xor(acc[0], 4, 64);
      acc[0] += __shfl_xor(acc[0], 2, 64);
      acc[0] += __shfl_xor(acc[0], 1, 64);   // lane holds row (lane>>3)
      float gi = __shfl(acc[0], 32*jsel + 0,  64);
      float gf = __shfl(acc[0], 32*jsel + 8,  64);
      float gg = __shfl(acc[0], 32*jsel + 16, 64);
      float go = __shfl(acc[0], 32*jsel + 24, 64);
      float cc = sigmf(gf+cgf)*cst + sigmf(gi+cgi)*tanhf(gg+cgg);
      float hh = sigmf(go+cgo)*tanhf(cc);
      cst = cc;
      if (lane < 2) {
        aswap64(y1c + (size_t)(s&(RING-1))*Hv + hg, mkword((uint32_t)(s+1), hh));
        ys1[(size_t)s*Hv + hg] = hh;   // plain store for postproc
      }
      if ((s & 511) == 511) {
        __syncthreads();   // drain all waves' ys1 stores (rare; keeps fence semantics)
        if (tid == 0) {
          __builtin_amdgcn_fence(__ATOMIC_RELEASE, "agent");
          astore32(iterflag + wg1, (uint32_t)((s >> 9) + 1));
        }
      }
    }
  } else {
    // ================= Postprocess (512 threads) =================
    const int p = bid - KA - KB;
    for (int r = tid; r < OUTv*Hv; r += 512) Wout_s[r] = Wout[r];
    for (int h = tid; h < Hv; h += 512) { gam_s[h] = gamma[h]; bet_s[h] = beta[h]; }
    float bo[OUTv];
#pragma unroll
    for (int o = 0; o < OUTv; ++o) bo[o] = bout[o];
    __syncthreads();

    for (int i = p; i < Tv; i += KPP) {
      const uint32_t tgt = (uint32_t)(i + 1);
      if (tid < 64) {
        for (;;) {
          uint32_t v = aload32(iterflag + (lane & 31));
          if (__all((int)(v >= tgt && v <= (uint32_t)Tv))) break;
          __builtin_amdgcn_s_sleep(16);
        }
      }
      __syncthreads();
      __builtin_amdgcn_fence(__ATOMIC_ACQUIRE, "agent");

      const float* Y = ys1 + (size_t)i * Bv * Hv;

      for (int h = tid; h < Hv; h += 512) {
        double sum = 0.0, sq = 0.0;
        for (int b = 0; b < Bv; ++b) {
          double v = (double)Y[(size_t)b*Hv + h];
          sum += v; sq += v*v;
        }
        double mu = sum * (1.0/512.0);
        double var = sq * (1.0/512.0) - mu*mu;
        if (var < 0.0) var = 0.0;
        mu_s[h]  = (float)mu;
        isd_s[h] = (float)(1.0 / sqrt(var + 1e-5));
      }
      __syncthreads();

      uint32_t k0, k1;
      threefry2x32(0u, 42u, 0u, (uint32_t)i, k0, k1);

      for (int b = tid; b < Bv; b += 512) {
        float lg[OUTv];
#pragma unroll
        for (int o = 0; o < OUTv; ++o) lg[o] = 0.f;
        const float* Yb = Y + (size_t)b * Hv;
        for (int h = 0; h < Hv; ++h) {
          float yn = (Yb[h] - mu_s[h]) * isd_s[h] * gam_s[h] + bet_s[h];
          float gv = expf(-yn*yn);
#pragma unroll
          for (int o = 0; o < OUTv; ++o) lg[o] = fmaf(gv, Wout_s[o*Hv + h], lg[o]);
        }
#pragma unroll
        for (int o = 0; o < OUTv; ++o) lg[o] += bo[o];

        int action; float la;
        if (i < 15) {
          float best = -3.0e38f; int bi = 0; float bl = lg[0];
#pragma unroll
          for (int o = 0; o < OUTv; ++o) {
            uint32_t bits = tf_bits32(k0, k1, (uint32_t)(b*12 + o));
            float z = gumbelf(bits) + lg[o];
            if (z > best) { best = z; bi = o; bl = lg[o]; }
          }
          action = bi; la = bl;
        } else {
          float best = -3.0e38f; int bi = 0; float bl = lg[S0v];
#pragma unroll
          for (int o = 0; o < 4; ++o) {
            uint32_t bits = tf_bits32(k0, k1, (uint32_t)(b*4 + o));
            float z = gumbelf(bits) + lg[S0v + o];
            if (z > best) { best = z; bi = o; bl = lg[S0v + o]; }
          }
          action = S0v + bi; la = bl;
        }

        float mx = lg[0];
#pragma unroll
        for (int o = 1; o < OUTv; ++o) mx = fmaxf(mx, lg[o]);
        float se = 0.f;
#pragma unroll
        for (int o = 0; o < OUTv; ++o) se += expf(lg[o] - mx);
        float lp = (la - mx) - logf(se);

        out[i*Bv + b]         = (float)action;
        out[STEPS + i*Bv + b] = lp;
      }
    }
  }
}

extern "C" void kernel_launch(void* const* d_in, const int* in_sizes, int n_in,
                              void* d_out, int out_size, void* d_ws, size_t ws_size,
                              hipStream_t stream) {
  const float* Wih0 = (const float*)d_in[0];
  const float* Whh0 = (const float*)d_in[1];
  const float* b0   = (const float*)d_in[2];
  const float* Wih1 = (const float*)d_in[3];
  const float* Whh1 = (const float*)d_in[4];
  const float* b1   = (const float*)d_in[5];
  const float* gam  = (const float*)d_in[6];
  const float* bet  = (const float*)d_in[7];
  const float* Wout = (const float*)d_in[8];
  const float* bout = (const float*)d_in[9];
  const float* h0   = (const float*)d_in[10];
  const float* c0   = (const float*)d_in[11];

  net_persistent<<<dim3(NBLK), dim3(512), 0, stream>>>(
      Wih0, Whh0, b0, Wih1, Whh1, b1, gam, bet, Wout, bout, h0, c0,
      (float*)d_out, (uint32_t*)d_ws);
}

// Round 4
// 41769.223 us; speedup vs baseline: 3.0324x; 2.6369x over previous
//
#include <hip/hip_runtime.h>
#include <stdint.h>
#include <math.h>

// Problem constants
#define Bv      512
#define INv     64
#define Hv      512
#define OUTv    12
#define Tv      31
#define S0v     8
#define STEPS   (Tv*Bv)        // 15872 sequential LSTM steps per layer

// Workgroup roles — r8 config (champion): 512-thread blocks, 48 LSTM sync domains.
// R4: identical structure to champion; ring polls widened to one 16B
// coherence-point load per thread (2 tag+value words), halving poll
// request count at the L3.
#define KA      16             // layer-0 WGs (32 h each, 4 h per wave)
#define KB      32             // layer-1 WGs (16 h each, 2 h per wave)
#define KPP     16             // postproc WGs
#define NBLK    (KA+KB+KPP)    // 64 blocks -> co-resident
#define RING    32             // comm ring depth (power of 2)

// ws layout (bytes), total 32,903,168:
//  [0, 128)       : iterflag u32[32]
//  [4096,   +128K): h0A u64[RING][512]  — read by L0
//  [135168, +128K): h0B u64[RING][512]  — read by L1
//  [266240, +128K): y1c u64[RING][512]  — read by L1 (+ L0 throttle, sparse)
//  [397312, ...)  : ys1 float[STEPS][512]  (plain, fenced per iteration)

// ---------------- threefry2x32 (JAX-exact) ----------------
__device__ __forceinline__ uint32_t rotl32(uint32_t v, int r){ return (v<<r)|(v>>(32-r)); }

__device__ __forceinline__ void threefry2x32(uint32_t k0, uint32_t k1,
                                             uint32_t x0, uint32_t x1,
                                             uint32_t& o0, uint32_t& o1) {
  uint32_t ks2 = k0 ^ k1 ^ 0x1BD11BDAu;
  x0 += k0; x1 += k1;
#define TFR(r) { x0 += x1; x1 = rotl32(x1, r); x1 ^= x0; }
  TFR(13) TFR(15) TFR(26) TFR(6)
  x0 += k1;  x1 += ks2 + 1u;
  TFR(17) TFR(29) TFR(16) TFR(24)
  x0 += ks2; x1 += k0 + 2u;
  TFR(13) TFR(15) TFR(26) TFR(6)
  x0 += k0;  x1 += k1 + 3u;
  TFR(17) TFR(29) TFR(16) TFR(24)
  x0 += k1;  x1 += ks2 + 4u;
  TFR(13) TFR(15) TFR(26) TFR(6)
  x0 += ks2; x1 += k0 + 5u;
#undef TFR
  o0 = x0; o1 = x1;
}

__device__ __forceinline__ uint32_t tf_bits32(uint32_t k0, uint32_t k1, uint32_t j) {
  uint32_t a, b;
  threefry2x32(k0, k1, 0u, j, a, b);
  return a ^ b;
}

__device__ __forceinline__ float u32_to_uniform(uint32_t bits) {
  float f = __uint_as_float(0x3F800000u | (bits >> 9)) - 1.0f;
  const float TINY = 1.17549435e-38f;
  return fmaxf(TINY, f + TINY);
}

__device__ __forceinline__ float gumbelf(uint32_t bits) {
  float u = u32_to_uniform(bits);
  return -logf(-logf(u));
}

__device__ __forceinline__ float sigmf(float x) {
  if (x >= 0.f) { float z = expf(-x); return 1.f/(1.f+z); }
  float z = expf(x); return z/(1.f+z);
}

// Butterfly: halve per-lane row-partials across lanes (xor mask m).
template<int N>
__device__ __forceinline__ void bfly_halve(float* v, int m) {
  int lane = threadIdx.x & 63;
  bool up = (lane & m) != 0;
#pragma unroll
  for (int j = 0; j < N/2; ++j) {
    float send = up ? v[j] : v[j + N/2];
    float recv = __shfl_xor(send, m, 64);
    v[j] = (up ? v[j + N/2] : v[j]) + recv;
  }
}

__device__ __forceinline__ uint64_t aload64(const uint64_t* p){
  return __hip_atomic_load(p, __ATOMIC_RELAXED, __HIP_MEMORY_SCOPE_AGENT);
}
__device__ __forceinline__ void astore64(uint64_t* p, uint64_t v){
  __hip_atomic_store(p, v, __ATOMIC_RELAXED, __HIP_MEMORY_SCOPE_AGENT);
}
__device__ __forceinline__ uint32_t aload32(const uint32_t* p){
  return __hip_atomic_load(p, __ATOMIC_RELAXED, __HIP_MEMORY_SCOPE_AGENT);
}
__device__ __forceinline__ void astore32(uint32_t* p, uint32_t v){
  __hip_atomic_store(p, v, __ATOMIC_RELAXED, __HIP_MEMORY_SCOPE_AGENT);
}
// One 16B load served at the coherence point (sc0 sc1 = bypass L1 and L2),
// covering two adjacent tag+value u64 words. Same freshness as the relaxed
// agent atomic load; a single transaction cannot tear an aligned 8B word.
typedef uint32_t u32x4_t __attribute__((ext_vector_type(4)));
__device__ __forceinline__ void aload128(const uint64_t* p, uint64_t& a, uint64_t& b){
  u32x4_t r;
  asm volatile("global_load_dwordx4 %0, %1, off sc0 sc1\n\ts_waitcnt vmcnt(0)"
               : "=&v"(r) : "v"(p) : "memory");
  a = ((uint64_t)r.y << 32) | (uint64_t)r.x;
  b = ((uint64_t)r.w << 32) | (uint64_t)r.z;
}
__device__ __forceinline__ uint32_t tagof(uint64_t w){ return (uint32_t)(w>>32); }
__device__ __forceinline__ float    valof(uint64_t w){ return __uint_as_float((uint32_t)w); }
__device__ __forceinline__ uint64_t mkword(uint32_t t, float v){
  return ((uint64_t)t<<32) | (uint64_t)__float_as_uint(v);
}

__global__ __launch_bounds__(512, 1)
void net_persistent(const float* __restrict__ Wih0, const float* __restrict__ Whh0,
                    const float* __restrict__ b0,
                    const float* __restrict__ Wih1, const float* __restrict__ Whh1,
                    const float* __restrict__ b1,
                    const float* __restrict__ gamma, const float* __restrict__ beta,
                    const float* __restrict__ Wout, const float* __restrict__ bout,
                    const float* __restrict__ h0in, const float* __restrict__ c0in,
                    float* __restrict__ out, uint32_t* __restrict__ wsu)
{
  uint32_t* iterflag = wsu;                              // [32]
  uint64_t* h0A = (uint64_t*)((char*)wsu + 4096);
  uint64_t* h0B = (uint64_t*)((char*)wsu + 4096 + (size_t)RING*Hv*8);
  uint64_t* y1c = (uint64_t*)((char*)wsu + 4096 + (size_t)2*RING*Hv*8);
  float*    ys1 = (float*)((char*)wsu + 4096 + (size_t)3*RING*Hv*8);

  const int bid  = blockIdx.x;
  const int tid  = threadIdx.x;
  const int wave = tid >> 6;
  const int lane = tid & 63;

  __shared__ float hbuf[2][Hv];      // L0 input double-buffer
  __shared__ float xbuf[2][2*Hv];    // L1 input double-buffer [x | hprev]
  __shared__ float Wout_s[OUTv*Hv];
  __shared__ float mu_s[Hv], isd_s[Hv], gam_s[Hv], bet_s[Hv];

  if (bid < KA) {
    // ================= Layer 0 (autonomous: x = ones folded) =================
    // 16 WGs x 512 threads; wave (0..7) owns 4 h-indices.
    const int hbase = bid*32;
    float w[128];
#pragma unroll
    for (int jl = 0; jl < 4; ++jl)
#pragma unroll
      for (int g = 0; g < 4; ++g) {
        int r = jl*4 + g;
        const float* rp = Whh0 + (size_t)(g*Hv + hbase + wave*4 + jl)*Hv;
#pragma unroll
        for (int k = 0; k < 2; ++k) {
          float4 q = *(const float4*)(rp + k*256 + lane*4);
          w[r*8+k*4+0]=q.x; w[r*8+k*4+1]=q.y; w[r*8+k*4+2]=q.z; w[r*8+k*4+3]=q.w;
        }
      }
    // per-lane gate constants (x = ones folded) + c-state for h-index lane&3
    const int jsel = lane & 3;
    const int hg = hbase + wave*4 + jsel;
    float cgi, cgf, cgg, cgo;
    {
      float s0=b0[0*Hv+hg], s1=b0[1*Hv+hg], s2=b0[2*Hv+hg], s3=b0[3*Hv+hg];
      for (int k = 0; k < INv; ++k) {
        s0 += Wih0[(size_t)(0*Hv+hg)*INv+k];
        s1 += Wih0[(size_t)(1*Hv+hg)*INv+k];
        s2 += Wih0[(size_t)(2*Hv+hg)*INv+k];
        s3 += Wih0[(size_t)(3*Hv+hg)*INv+k];
      }
      cgi=s0; cgf=s1; cgg=s2; cgo=s3;
    }
    float cst = c0in[hg];

    for (int s = 0; s < STEPS; ++s) {
      const int par = s & 1;
      // ring throttle every 16 steps: require L1 consumed h0 tag >= s-16
      // before overwriting slots s-32..s-17 (L1 progress via y1c tags).
      if ((s & 15) == 0 && s >= 32) {
        const uint64_t* tp = y1c + (size_t)((s-17)&(RING-1))*Hv + lane*8;
        uint32_t need = (uint32_t)(s - 16);
        for (;;) {
          uint32_t t = tagof(aload64(tp));
          if (__all((int)(t >= need && t <= (uint32_t)STEPS))) break;
          __builtin_amdgcn_s_sleep(1);
        }
      }
      // phase A: poll previous h into LDS — 2 words per polling thread (16B)
      if (s == 0) {
        hbuf[0][tid] = h0in[tid];
      } else if (tid < 256) {
        const uint64_t* src = h0A + (size_t)((s-1)&(RING-1))*Hv + 2*tid;
        const uint32_t want = (uint32_t)s;
        uint64_t a, b2;
        for (;;) {
          aload128(src, a, b2);
          if (tagof(a) == want && tagof(b2) == want) break;
        }
        hbuf[par][2*tid]   = valof(a);
        hbuf[par][2*tid+1] = valof(b2);
      }
      __syncthreads();
      // compute: 16 rows x 8 cols per lane
      const float4* hv = (const float4*)(hbuf[par]);
      float4 vA = hv[lane], vB = hv[64 + lane];
      float acc[16];
#pragma unroll
      for (int r = 0; r < 16; ++r) {
        float a = 0.f;
        a = fmaf(w[r*8+0], vA.x, a); a = fmaf(w[r*8+1], vA.y, a);
        a = fmaf(w[r*8+2], vA.z, a); a = fmaf(w[r*8+3], vA.w, a);
        a = fmaf(w[r*8+4], vB.x, a); a = fmaf(w[r*8+5], vB.y, a);
        a = fmaf(w[r*8+6], vB.z, a); a = fmaf(w[r*8+7], vB.w, a);
        acc[r] = a;
      }
      bfly_halve<16>(acc, 32);
      bfly_halve<8>(acc, 16);
      bfly_halve<4>(acc, 8);
      bfly_halve<2>(acc, 4);
      acc[0] += __shfl_xor(acc[0], 2, 64);
      acc[0] += __shfl_xor(acc[0], 1, 64);   // lane holds row (lane>>2)
      // every lane gathers the 4 gates of h-index jsel
      float gi = __shfl(acc[0], 16*jsel + 0,  64);
      float gf = __shfl(acc[0], 16*jsel + 4,  64);
      float gg = __shfl(acc[0], 16*jsel + 8,  64);
      float go = __shfl(acc[0], 16*jsel + 12, 64);
      float cc = sigmf(gf+cgf)*cst + sigmf(gi+cgi)*tanhf(gg+cgg);
      float hh = sigmf(go+cgo)*tanhf(cc);
      cst = cc;
      if (lane < 8) {   // lanes 0-3 -> replica A (L0 readers); 4-7 -> B (L1 readers)
        uint64_t* dst = (lane < 4) ? h0A : h0B;
        astore64(dst + (size_t)(s&(RING-1))*Hv + hg, mkword((uint32_t)(s+1), hh));
      }
    }
  } else if (bid < KA + KB) {
    // ================= Layer 1 =================
    // 32 WGs x 512 threads; wave (0..7) owns 2 h-indices.
    const int wg1 = bid - KA;
    const int hbase = wg1*16;
    float w[128];
#pragma unroll
    for (int jl = 0; jl < 2; ++jl)
#pragma unroll
      for (int g = 0; g < 4; ++g) {
        int r = jl*4 + g;
        int row = g*Hv + hbase + wave*2 + jl;
#pragma unroll
        for (int k = 0; k < 4; ++k) {
          int col = k*256 + lane*4;
          const float* M = (col < Hv) ? (Wih1 + (size_t)row*Hv + col)
                                      : (Whh1 + (size_t)row*Hv + (col - Hv));
          float4 q = *(const float4*)M;
          w[r*16+k*4+0]=q.x; w[r*16+k*4+1]=q.y; w[r*16+k*4+2]=q.z; w[r*16+k*4+3]=q.w;
        }
      }
    const int jsel = lane & 1;
    const int hg = hbase + wave*2 + jsel;
    float cgi = b1[0*Hv+hg], cgf = b1[1*Hv+hg],
          cgg = b1[2*Hv+hg], cgo = b1[3*Hv+hg];
    float cst = c0in[Hv + hg];

    for (int s = 0; s < STEPS; ++s) {
      const int par = s & 1;
      // phase A: poll x = h0[s] (tag s+1, replica B) and hprev = y1[s-1] (tag s)
      // 2 words per thread via one 16B load: threads 0..255 cover x, 256..511 hprev.
      {
        int j0 = tid*2;
        if (j0 < Hv) {
          const uint64_t* src = h0B + (size_t)(s&(RING-1))*Hv + j0;
          const uint32_t want = (uint32_t)(s+1);
          uint64_t a, b2;
          for (;;) {
            aload128(src, a, b2);
            if (tagof(a) == want && tagof(b2) == want) break;
          }
          xbuf[par][j0] = valof(a); xbuf[par][j0+1] = valof(b2);
        } else {
          if (s == 0) {
            xbuf[0][j0]   = h0in[j0];     // h0in[512..1023] = layer-1 h0
            xbuf[0][j0+1] = h0in[j0+1];
          } else {
            const uint64_t* src = y1c + (size_t)((s-1)&(RING-1))*Hv + (j0 - Hv);
            const uint32_t want = (uint32_t)s;
            uint64_t a, b2;
            for (;;) {
              aload128(src, a, b2);
              if (tagof(a) == want && tagof(b2) == want) break;
            }
            xbuf[par][j0] = valof(a); xbuf[par][j0+1] = valof(b2);
          }
        }
      }
      __syncthreads();
      // compute: 8 rows x 16 cols per lane
      const float4* xv = (const float4*)(xbuf[par]);
      float4 v0 = xv[lane], v1 = xv[64+lane], v2 = xv[128+lane], v3 = xv[192+lane];
      float acc[8];
#pragma unroll
      for (int r = 0; r < 8; ++r) {
        float a = 0.f;
        a = fmaf(w[r*16+ 0], v0.x, a); a = fmaf(w[r*16+ 1], v0.y, a);
        a = fmaf(w[r*16+ 2], v0.z, a); a = fmaf(w[r*16+ 3], v0.w, a);
        a = fmaf(w[r*16+ 4], v1.x, a); a = fmaf(w[r*16+ 5], v1.y, a);
        a = fmaf(w[r*16+ 6], v1.z, a); a = fmaf(w[r*16+ 7], v1.w, a);
        a = fmaf(w[r*16+ 8], v2.x, a); a = fmaf(w[r*16+ 9], v2.y, a);
        a = fmaf(w[r*16+10], v2.z, a); a = fmaf(w[r*16+11], v2.w, a);
        a = fmaf(w[r*16+12], v3.x, a); a = fmaf(w[r*16+13], v3.y, a);
        a = fmaf(w[r*16+14], v3.z, a); a = fmaf(w[r*16+15], v3.w, a);
        acc[r] = a;
      }
      bfly_halve<8>(acc, 32);
      bfly_halve<4>(acc, 16);
      bfly_halve<2>(acc, 8);
      acc[0] += __shfl_xor(acc[0], 4, 64);
      acc[0] += __shfl_xor(acc[0], 2, 64);
      acc[0] += __shfl_xor(acc[0], 1, 64);   // lane holds row (lane>>3)
      float gi = __shfl(acc[0], 32*jsel + 0,  64);
      float gf = __shfl(acc[0], 32*jsel + 8,  64);
      float gg = __shfl(acc[0], 32*jsel + 16, 64);
      float go = __shfl(acc[0], 32*jsel + 24, 64);
      float cc = sigmf(gf+cgf)*cst + sigmf(gi+cgi)*tanhf(gg+cgg);
      float hh = sigmf(go+cgo)*tanhf(cc);
      cst = cc;
      if (lane < 2) {
        astore64(y1c + (size_t)(s&(RING-1))*Hv + hg, mkword((uint32_t)(s+1), hh));
        ys1[(size_t)s*Hv + hg] = hh;   // plain store for postproc
      }
      if ((s & 511) == 511) {
        __syncthreads();   // drain all waves' ys1 stores
        if (tid == 0) {
          __builtin_amdgcn_fence(__ATOMIC_RELEASE, "agent");
          astore32(iterflag + wg1, (uint32_t)((s >> 9) + 1));
        }
      }
    }
  } else {
    // ================= Postprocess (512 threads) =================
    const int p = bid - KA - KB;
    for (int r = tid; r < OUTv*Hv; r += 512) Wout_s[r] = Wout[r];
    for (int h = tid; h < Hv; h += 512) { gam_s[h] = gamma[h]; bet_s[h] = beta[h]; }
    float bo[OUTv];
#pragma unroll
    for (int o = 0; o < OUTv; ++o) bo[o] = bout[o];
    __syncthreads();

    for (int i = p; i < Tv; i += KPP) {
      const uint32_t tgt = (uint32_t)(i + 1);
      if (tid < 64) {
        for (;;) {
          uint32_t v = aload32(iterflag + (lane & 31));
          if (__all((int)(v >= tgt && v <= (uint32_t)Tv))) break;
          __builtin_amdgcn_s_sleep(16);
        }
      }
      __syncthreads();
      __builtin_amdgcn_fence(__ATOMIC_ACQUIRE, "agent");

      const float* Y = ys1 + (size_t)i * Bv * Hv;

      for (int h = tid; h < Hv; h += 512) {
        double sum = 0.0, sq = 0.0;
        for (int b = 0; b < Bv; ++b) {
          double v = (double)Y[(size_t)b*Hv + h];
          sum += v; sq += v*v;
        }
        double mu = sum * (1.0/512.0);
        double var = sq * (1.0/512.0) - mu*mu;
        if (var < 0.0) var = 0.0;
        mu_s[h]  = (float)mu;
        isd_s[h] = (float)(1.0 / sqrt(var + 1e-5));
      }
      __syncthreads();

      uint32_t k0, k1;
      threefry2x32(0u, 42u, 0u, (uint32_t)i, k0, k1);

      for (int b = tid; b < Bv; b += 512) {
        float lg[OUTv];
#pragma unroll
        for (int o = 0; o < OUTv; ++o) lg[o] = 0.f;
        const float* Yb = Y + (size_t)b * Hv;
        for (int h = 0; h < Hv; ++h) {
          float yn = (Yb[h] - mu_s[h]) * isd_s[h] * gam_s[h] + bet_s[h];
          float gv = expf(-yn*yn);
#pragma unroll
          for (int o = 0; o < OUTv; ++o) lg[o] = fmaf(gv, Wout_s[o*Hv + h], lg[o]);
        }
#pragma unroll
        for (int o = 0; o < OUTv; ++o) lg[o] += bo[o];

        int action; float la;
        if (i < 15) {
          float best = -3.0e38f; int bi = 0; float bl = lg[0];
#pragma unroll
          for (int o = 0; o < OUTv; ++o) {
            uint32_t bits = tf_bits32(k0, k1, (uint32_t)(b*12 + o));
            float z = gumbelf(bits) + lg[o];
            if (z > best) { best = z; bi = o; bl = lg[o]; }
          }
          action = bi; la = bl;
        } else {
          float best = -3.0e38f; int bi = 0; float bl = lg[S0v];
#pragma unroll
          for (int o = 0; o < 4; ++o) {
            uint32_t bits = tf_bits32(k0, k1, (uint32_t)(b*4 + o));
            float z = gumbelf(bits) + lg[S0v + o];
            if (z > best) { best = z; bi = o; bl = lg[S0v + o]; }
          }
          action = S0v + bi; la = bl;
        }

        float mx = lg[0];
#pragma unroll
        for (int o = 1; o < OUTv; ++o) mx = fmaxf(mx, lg[o]);
        float se = 0.f;
#pragma unroll
        for (int o = 0; o < OUTv; ++o) se += expf(lg[o] - mx);
        float lp = (la - mx) - logf(se);

        out[i*Bv + b]         = (float)action;
        out[STEPS + i*Bv + b] = lp;
      }
    }
  }
}

extern "C" void kernel_launch(void* const* d_in, const int* in_sizes, int n_in,
                              void* d_out, int out_size, void* d_ws, size_t ws_size,
                              hipStream_t stream) {
  const float* Wih0 = (const float*)d_in[0];
  const float* Whh0 = (const float*)d_in[1];
  const float* b0   = (const float*)d_in[2];
  const float* Wih1 = (const float*)d_in[3];
  const float* Whh1 = (const float*)d_in[4];
  const float* b1   = (const float*)d_in[5];
  const float* gam  = (const float*)d_in[6];
  const float* bet  = (const float*)d_in[7];
  const float* Wout = (const float*)d_in[8];
  const float* bout = (const float*)d_in[9];
  const float* h0   = (const float*)d_in[10];
  const float* c0   = (const float*)d_in[11];

  net_persistent<<<dim3(NBLK), dim3(512), 0, stream>>>(
      Wih0, Whh0, b0, Wih1, Whh1, b1, gam, bet, Wout, bout, h0, c0,
      (float*)d_out, (uint32_t*)d_ws);
}